// Round 1
// baseline (55.771 us; speedup 1.0000x reference)
//
#include <hip/hip_runtime.h>
#include <math.h>

#define B_ 128
#define N_ 16800
#define NEG_RATIO_ 3
#define NTHREADS 1024
#define NWAVES (NTHREADS / 64)

// One block per batch row. Streams the row, computes SmoothL1/BCE and the
// positive-set reductions, stores labels_neg float bits in LDS, then does an
// exact k-th-largest radix select (4 rounds x 8 bits, MSB first) to get the
// hard-negative-mining threshold, and sums the selected negatives.
// Non-negative floats compare identically as uint32 bit patterns.
__global__ __launch_bounds__(NTHREADS) void row_loss_kernel(
    const float* __restrict__ pbboxs,
    const float* __restrict__ plabels,
    const float* __restrict__ gbboxs,
    const float* __restrict__ glabels,
    const float* __restrict__ ancs,
    float* __restrict__ row_lb,   // [B] sum of pos * sl1
    float* __restrict__ row_ll,   // [B] sum of bce * (pos + mask_neg)
    int*   __restrict__ row_pn)   // [B] pos_num
{
    __shared__ unsigned int s_lneg[N_];   // 67200 B
    __shared__ unsigned int s_hist[256];
    __shared__ float s_rf[NWAVES];
    __shared__ float s_rf2[NWAVES];
    __shared__ int   s_ri[NWAVES];
    __shared__ float s_bf[2];             // [0]=loss_bboxs, [1]=sum_pos_bce
    __shared__ int   s_bi[4];             // [0]=pos_num, [1]=sel digit, [2]=new remk

    const int b    = blockIdx.x;
    const int tid  = threadIdx.x;
    const int lane = tid & 63;
    const int wave = tid >> 6;

    const float4* p4 = (const float4*)(pbboxs + (size_t)b * N_ * 4);
    const float4* g4 = (const float4*)(gbboxs + (size_t)b * N_ * 4);
    const float4* a4 = (const float4*)ancs;
    const float*  pl = plabels + (size_t)b * N_;
    const float*  gl = glabels + (size_t)b * N_;

    float acc_lb   = 0.f;   // sum pos * sl1
    float acc_pbce = 0.f;   // sum pos * bce
    int   acc_pn   = 0;     // pos count

    for (int n = tid; n < N_; n += NTHREADS) {
        float4 p = p4[n];
        float4 g = g4[n];
        float4 a = a4[n];
        float  x = pl[n];
        float  y = gl[n];

        // encode GT vs anchors (SCALE_XY=10, SCALE_WH=5)
        float dx = 10.f * (g.x - a.x) / a.z;
        float dy = 10.f * (g.y - a.y) / a.w;
        float dw = 5.f * logf(g.z / a.z);
        float dh = 5.f * logf(g.w / a.w);

        // SmoothL1 (beta=1) summed over coord dim
        float d0 = p.x - dx, d1 = p.y - dy, d2 = p.z - dw, d3 = p.w - dh;
        float a0 = fabsf(d0), a1 = fabsf(d1), a2 = fabsf(d2), a3 = fabsf(d3);
        float sl1 = ((a0 < 1.f) ? 0.5f * d0 * d0 : a0 - 0.5f)
                  + ((a1 < 1.f) ? 0.5f * d1 * d1 : a1 - 0.5f)
                  + ((a2 < 1.f) ? 0.5f * d2 * d2 : a2 - 0.5f)
                  + ((a3 < 1.f) ? 0.5f * d3 * d3 : a3 - 0.5f);

        // numerically stable BCEWithLogits; bce >= 0 always
        float bce = fmaxf(x, 0.f) - x * y + log1pf(expf(-fabsf(x)));

        bool pos = (y > 0.f);
        float lneg = pos ? 0.f : bce;
        s_lneg[n] = __float_as_uint(lneg);

        if (pos) { acc_lb += sl1; acc_pbce += bce; acc_pn += 1; }
    }

    // block reduce: wave shuffle then cross-wave via LDS
    #pragma unroll
    for (int off = 32; off > 0; off >>= 1) {
        acc_lb   += __shfl_down(acc_lb, off);
        acc_pbce += __shfl_down(acc_pbce, off);
        acc_pn   += __shfl_down(acc_pn, off);
    }
    if (lane == 0) { s_rf[wave] = acc_lb; s_rf2[wave] = acc_pbce; s_ri[wave] = acc_pn; }
    __syncthreads();   // also makes s_lneg visible block-wide
    if (tid == 0) {
        float t_lb = 0.f, t_pbce = 0.f; int t_pn = 0;
        for (int w = 0; w < NWAVES; ++w) { t_lb += s_rf[w]; t_pbce += s_rf2[w]; t_pn += s_ri[w]; }
        s_bf[0] = t_lb; s_bf[1] = t_pbce; s_bi[0] = t_pn;
    }
    __syncthreads();

    const int pos_num = s_bi[0];
    int neg_num = NEG_RATIO_ * pos_num;
    if (neg_num > N_) neg_num = N_;

    if (neg_num == 0) {   // uniform branch: no negatives selected
        if (tid == 0) {
            row_lb[b] = s_bf[0];
            row_ll[b] = s_bf[1];
            row_pn[b] = pos_num;
        }
        return;
    }

    // ---- radix select: find t = neg_num-th largest of s_lneg (as uint) ----
    unsigned int prefix = 0u;
    unsigned int remk   = (unsigned int)neg_num;   // invariant: 1 <= remk

    for (int shift = 24; shift >= 0; shift -= 8) {
        const unsigned int pmask = (shift == 24) ? 0u : (0xFFFFFFFFu << (shift + 8));
        __syncthreads();
        if (tid < 256) s_hist[tid] = 0u;
        __syncthreads();
        for (int n = tid; n < N_; n += NTHREADS) {
            unsigned int v = s_lneg[n];
            if ((v & pmask) == prefix)
                atomicAdd(&s_hist[(v >> shift) & 255u], 1u);
        }
        __syncthreads();
        if (wave == 0) {
            // lane handles 4 consecutive bins; suffix-sum across lanes via shfl
            unsigned int c0 = s_hist[4 * lane + 0];
            unsigned int c1 = s_hist[4 * lane + 1];
            unsigned int c2 = s_hist[4 * lane + 2];
            unsigned int c3 = s_hist[4 * lane + 3];
            unsigned int suf = c0 + c1 + c2 + c3;
            #pragma unroll
            for (int off = 1; off < 64; off <<= 1) {
                unsigned int o = __shfl_down(suf, off);
                if (lane + off < 64) suf += o;
            }
            // suffix counts at each of this lane's 4 digits
            unsigned int s0 = suf;
            unsigned int s1 = s0 - c0;
            unsigned int s2 = s1 - c1;
            unsigned int s3 = s2 - c2;
            unsigned int s4 = s3 - c3;   // = suffix at next group start
            int d = -1; unsigned int nk = 0u;
            if      (s3 >= remk && s4 < remk) { d = 4 * lane + 3; nk = remk - s4; }
            else if (s2 >= remk && s3 < remk) { d = 4 * lane + 2; nk = remk - s3; }
            else if (s1 >= remk && s2 < remk) { d = 4 * lane + 1; nk = remk - s2; }
            else if (s0 >= remk && s1 < remk) { d = 4 * lane + 0; nk = remk - s1; }
            if (d >= 0) { s_bi[1] = d; s_bi[2] = (int)nk; }   // exactly one lane fires
        }
        __syncthreads();
        prefix |= ((unsigned int)s_bi[1]) << shift;
        remk = (unsigned int)s_bi[2];
    }

    // sum of strictly-greater values; ties at t all contribute exactly t each
    float sum_top = 0.f;
    for (int n = tid; n < N_; n += NTHREADS) {
        unsigned int v = s_lneg[n];
        if (v > prefix) sum_top += __uint_as_float(v);
    }
    #pragma unroll
    for (int off = 32; off > 0; off >>= 1) sum_top += __shfl_down(sum_top, off);
    __syncthreads();
    if (lane == 0) s_rf[wave] = sum_top;
    __syncthreads();
    if (tid == 0) {
        float st = 0.f;
        for (int w = 0; w < NWAVES; ++w) st += s_rf[w];
        float t = __uint_as_float(prefix);
        row_ll[b] = s_bf[1] + st + (float)remk * t;
        row_lb[b] = s_bf[0];
        row_pn[b] = pos_num;
    }
}

// Single-block epilogue: the B=128 means with eps-clipped pos_cnt.
__global__ __launch_bounds__(128) void final_kernel(
    const float* __restrict__ row_lb,
    const float* __restrict__ row_ll,
    const int*   __restrict__ row_pn,
    float* __restrict__ out)
{
    const int tid  = threadIdx.x;
    const int lane = tid & 63;
    const int wave = tid >> 6;

    float lb_t = 0.f, ll_t = 0.f, w_t = 0.f;
    if (tid < B_) {
        int pn = row_pn[tid];
        float nm = (pn > 0) ? 1.f : 0.f;
        float pc = fmaxf((float)pn, 1.1920929e-7f);   // jnp.finfo(f32).eps clip
        lb_t = row_lb[tid] * nm / pc;
        ll_t = row_ll[tid] * nm / pc;
        w_t  = nm / pc;
    }
    #pragma unroll
    for (int off = 32; off > 0; off >>= 1) {
        lb_t += __shfl_down(lb_t, off);
        ll_t += __shfl_down(ll_t, off);
        w_t  += __shfl_down(w_t, off);
    }
    __shared__ float sh[3][2];
    if (lane == 0) { sh[0][wave] = lb_t; sh[1][wave] = ll_t; sh[2][wave] = w_t; }
    __syncthreads();
    if (tid == 0) {
        float lb = (sh[0][0] + sh[0][1]) * (1.f / B_);
        float ll = (sh[1][0] + sh[1][1]) * (1.f / B_);
        float wm = (sh[2][0] + sh[2][1]) * (1.f / B_);
        out[0] = (lb + ll) * wm;   // total_loss
        out[1] = lb;
        out[2] = ll;
    }
}

extern "C" void kernel_launch(void* const* d_in, const int* in_sizes, int n_in,
                              void* d_out, int out_size, void* d_ws, size_t ws_size,
                              hipStream_t stream) {
    const float* pbboxs  = (const float*)d_in[0];
    const float* plabels = (const float*)d_in[1];
    const float* gbboxs  = (const float*)d_in[2];
    const float* glabels = (const float*)d_in[3];
    const float* ancs    = (const float*)d_in[4];
    float* out = (float*)d_out;

    float* row_lb = (float*)d_ws;
    float* row_ll = row_lb + B_;
    int*   row_pn = (int*)(row_ll + B_);

    row_loss_kernel<<<B_, NTHREADS, 0, stream>>>(
        pbboxs, plabels, gbboxs, glabels, ancs, row_lb, row_ll, row_pn);
    final_kernel<<<1, 128, 0, stream>>>(row_lb, row_ll, row_pn, out);
}

// Round 2
// 38.079 us; speedup vs baseline: 1.4646x; 1.4646x over previous
//
#include <hip/hip_runtime.h>
#include <math.h>

#define B_ 128
#define N_ 16800
#define N4_ 4200            // N_/4
#define NEG_RATIO_ 3
#define NTHREADS 1024
#define NWAVES 16
#define NBINS 2048
#define FLT_EPS_ 1.1920929e-7f

// Suffix-scan a 2048-bin histogram (wave 0 only), find digit d with
// S(d) >= remk > S(d+1), write {d, remk - S(d+1)} to s_sel. Ends with a
// block-wide barrier so all threads can read s_sel afterwards.
__device__ __forceinline__ void hist_select(const unsigned int* __restrict__ h,
                                            unsigned int remk, int lane, int wave,
                                            unsigned int* s_sel)
{
    if (wave == 0) {
        unsigned int c[32], lsum = 0u;
        #pragma unroll
        for (int j = 0; j < 32; ++j) { c[j] = h[lane * 32 + j]; lsum += c[j]; }
        unsigned int suf = lsum;
        #pragma unroll
        for (int off = 1; off < 64; off <<= 1) {
            unsigned int o = __shfl_down(suf, off);
            if (lane + off < 64) suf += o;
        }
        // suf = sum over bins owned by lanes >= lane
        unsigned int r = suf;
        #pragma unroll
        for (int j = 0; j < 32; ++j) {
            unsigned int scur = r; r -= c[j];
            if (scur >= remk && r < remk) {
                s_sel[0] = (unsigned int)(lane * 32 + j);
                s_sel[1] = remk - r;
            }
        }
    }
    __syncthreads();
}

// One block per batch row. Dense reads: plabels+glabels rows only. Box data
// fetched sparsely at positive anchors (~2%). Exact k-th-largest radix select
// (3 rounds: 11/11/10 bits) over labels_neg bit patterns held in LDS.
// Final B-mean folded in via last-block atomic protocol.
__global__ __launch_bounds__(NTHREADS) void fused_loss_kernel(
    const float* __restrict__ pbboxs,
    const float* __restrict__ plabels,
    const float* __restrict__ gbboxs,
    const float* __restrict__ glabels,
    const float* __restrict__ ancs,
    float* __restrict__ g_acc,         // [3] zeroed each call
    unsigned int* __restrict__ g_cnt,  // [1] zeroed each call
    float* __restrict__ out)
{
    __shared__ __align__(16) unsigned int s_lneg[N_];   // 67200 B
    __shared__ unsigned int s_hist[NBINS];              // 8192 B
    __shared__ float s_rf[NWAVES], s_rf2[NWAVES];
    __shared__ int   s_ri[NWAVES];
    __shared__ float s_bf[2];                            // [0]=lb, [1]=pos_bce
    __shared__ int   s_bi[1];                            // pos_num
    __shared__ unsigned int s_sel[2];                    // digit, remk

    const int b    = blockIdx.x;
    const int tid  = threadIdx.x;
    const int lane = tid & 63;
    const int wave = tid >> 6;

    for (int i = tid; i < NBINS; i += NTHREADS) s_hist[i] = 0u;
    __syncthreads();

    const float4* pl4 = (const float4*)(plabels + (size_t)b * N_);
    const float4* gl4 = (const float4*)(glabels + (size_t)b * N_);
    const float4* p4  = (const float4*)(pbboxs + (size_t)b * N_ * 4);
    const float4* g4  = (const float4*)(gbboxs + (size_t)b * N_ * 4);
    const float4* a4  = (const float4*)ancs;

    float acc_lb = 0.f, acc_pbce = 0.f;
    int   acc_pn = 0;

    // ---- pass 1: bce for all anchors, sl1 at sparse positives, LDS store +
    //      round-1 histogram (top 11 bits) ----
    for (int i = tid; i < N4_; i += NTHREADS) {
        float4 xv = pl4[i];
        float4 yv = gl4[i];
        float xa[4] = {xv.x, xv.y, xv.z, xv.w};
        float ya[4] = {yv.x, yv.y, yv.z, yv.w};
        unsigned int ob[4];
        #pragma unroll
        for (int j = 0; j < 4; ++j) {
            float x = xa[j], y = ya[j];
            float bce = fmaxf(x, 0.f) - x * y + __logf(1.f + __expf(-fabsf(x)));
            bool pos = (y > 0.f);
            float lneg = pos ? 0.f : bce;
            unsigned int vb = __float_as_uint(lneg);
            ob[j] = vb;
            atomicAdd(&s_hist[vb >> 21], 1u);
            if (pos) {
                acc_pbce += bce;
                acc_pn   += 1;
                int n = 4 * i + j;
                float4 p = p4[n], g = g4[n], a = a4[n];
                float d0 = p.x - 10.f * __fdividef(g.x - a.x, a.z);
                float d1 = p.y - 10.f * __fdividef(g.y - a.y, a.w);
                float d2 = p.z - 5.f * __logf(__fdividef(g.z, a.z));
                float d3 = p.w - 5.f * __logf(__fdividef(g.w, a.w));
                float a0 = fabsf(d0), a1 = fabsf(d1), a2 = fabsf(d2), a3 = fabsf(d3);
                acc_lb += ((a0 < 1.f) ? 0.5f * d0 * d0 : a0 - 0.5f)
                        + ((a1 < 1.f) ? 0.5f * d1 * d1 : a1 - 0.5f)
                        + ((a2 < 1.f) ? 0.5f * d2 * d2 : a2 - 0.5f)
                        + ((a3 < 1.f) ? 0.5f * d3 * d3 : a3 - 0.5f);
            }
        }
        uint4 st; st.x = ob[0]; st.y = ob[1]; st.z = ob[2]; st.w = ob[3];
        ((uint4*)s_lneg)[i] = st;
    }

    // block reduce (butterfly within wave, then cross-wave)
    #pragma unroll
    for (int off = 32; off > 0; off >>= 1) {
        acc_lb   += __shfl_xor(acc_lb, off);
        acc_pbce += __shfl_xor(acc_pbce, off);
        acc_pn   += __shfl_xor(acc_pn, off);
    }
    if (lane == 0) { s_rf[wave] = acc_lb; s_rf2[wave] = acc_pbce; s_ri[wave] = acc_pn; }
    __syncthreads();   // also publishes s_lneg + round-1 hist
    if (tid == 0) {
        float t_lb = 0.f, t_pbce = 0.f; int t_pn = 0;
        for (int w = 0; w < NWAVES; ++w) { t_lb += s_rf[w]; t_pbce += s_rf2[w]; t_pn += s_ri[w]; }
        s_bf[0] = t_lb; s_bf[1] = t_pbce; s_bi[0] = t_pn;
    }
    __syncthreads();

    const int pos_num = s_bi[0];
    int neg_num = NEG_RATIO_ * pos_num;
    if (neg_num > N_) neg_num = N_;

    float sum_sel = 0.f;   // only meaningful on tid 0

    if (neg_num > 0) {     // block-uniform branch
        // ---- round 1: digit from bits [31:21] (hist already built) ----
        hist_select(s_hist, (unsigned int)neg_num, lane, wave, s_sel);
        unsigned int pref = s_sel[0];          // 11-bit prefix
        unsigned int remk = s_sel[1];

        // ---- round 2: bits [20:10] among candidates ----
        for (int i = tid; i < NBINS; i += NTHREADS) s_hist[i] = 0u;
        __syncthreads();
        for (int i = tid; i < N4_; i += NTHREADS) {
            uint4 v = ((const uint4*)s_lneg)[i];
            if ((v.x >> 21) == pref) atomicAdd(&s_hist[(v.x >> 10) & 0x7FFu], 1u);
            if ((v.y >> 21) == pref) atomicAdd(&s_hist[(v.y >> 10) & 0x7FFu], 1u);
            if ((v.z >> 21) == pref) atomicAdd(&s_hist[(v.z >> 10) & 0x7FFu], 1u);
            if ((v.w >> 21) == pref) atomicAdd(&s_hist[(v.w >> 10) & 0x7FFu], 1u);
        }
        __syncthreads();
        hist_select(s_hist, remk, lane, wave, s_sel);
        pref = (pref << 11) | s_sel[0];        // 22-bit prefix
        remk = s_sel[1];

        // ---- round 3: bits [9:0] among candidates (1024 bins; top half stays 0) ----
        for (int i = tid; i < NBINS; i += NTHREADS) s_hist[i] = 0u;
        __syncthreads();
        for (int i = tid; i < N4_; i += NTHREADS) {
            uint4 v = ((const uint4*)s_lneg)[i];
            if ((v.x >> 10) == pref) atomicAdd(&s_hist[v.x & 0x3FFu], 1u);
            if ((v.y >> 10) == pref) atomicAdd(&s_hist[v.y & 0x3FFu], 1u);
            if ((v.z >> 10) == pref) atomicAdd(&s_hist[v.z & 0x3FFu], 1u);
            if ((v.w >> 10) == pref) atomicAdd(&s_hist[v.w & 0x3FFu], 1u);
        }
        __syncthreads();
        hist_select(s_hist, remk, lane, wave, s_sel);
        unsigned int t_bits = (pref << 10) | s_sel[0];
        remk = s_sel[1];

        // ---- sum of strictly-greater; ties contribute remk * t ----
        float stv = 0.f;
        for (int i = tid; i < N4_; i += NTHREADS) {
            uint4 v = ((const uint4*)s_lneg)[i];
            if (v.x > t_bits) stv += __uint_as_float(v.x);
            if (v.y > t_bits) stv += __uint_as_float(v.y);
            if (v.z > t_bits) stv += __uint_as_float(v.z);
            if (v.w > t_bits) stv += __uint_as_float(v.w);
        }
        #pragma unroll
        for (int off = 32; off > 0; off >>= 1) stv += __shfl_xor(stv, off);
        if (lane == 0) s_rf[wave] = stv;
        __syncthreads();
        if (tid == 0) {
            float tot = 0.f;
            for (int w = 0; w < NWAVES; ++w) tot += s_rf[w];
            sum_sel = tot + (float)remk * __uint_as_float(t_bits);
        }
    }

    // ---- per-row contribution + last-block final reduction ----
    if (tid == 0) {
        float lb = s_bf[0];
        float ll = s_bf[1] + sum_sel;
        float nm = (pos_num > 0) ? 1.f : 0.f;
        float pc = fmaxf((float)pos_num, FLT_EPS_);
        atomicAdd(&g_acc[0], lb * nm / pc);
        atomicAdd(&g_acc[1], ll * nm / pc);
        atomicAdd(&g_acc[2], nm / pc);
        __threadfence();
        unsigned int old = atomicAdd(g_cnt, 1u);
        if (old == (unsigned int)(B_ - 1)) {
            float LB = atomicAdd(&g_acc[0], 0.f) * (1.f / B_);
            float LL = atomicAdd(&g_acc[1], 0.f) * (1.f / B_);
            float W  = atomicAdd(&g_acc[2], 0.f) * (1.f / B_);
            out[0] = (LB + LL) * W;
            out[1] = LB;
            out[2] = LL;
        }
    }
}

extern "C" void kernel_launch(void* const* d_in, const int* in_sizes, int n_in,
                              void* d_out, int out_size, void* d_ws, size_t ws_size,
                              hipStream_t stream) {
    const float* pbboxs  = (const float*)d_in[0];
    const float* plabels = (const float*)d_in[1];
    const float* gbboxs  = (const float*)d_in[2];
    const float* glabels = (const float*)d_in[3];
    const float* ancs    = (const float*)d_in[4];
    float* out = (float*)d_out;

    float* g_acc = (float*)d_ws;
    unsigned int* g_cnt = (unsigned int*)d_ws + 3;

    // zero the 3 accumulators + arrival counter (16 B) each call
    hipMemsetAsync(d_ws, 0, 16, stream);

    fused_loss_kernel<<<B_, NTHREADS, 0, stream>>>(
        pbboxs, plabels, gbboxs, glabels, ancs, g_acc, g_cnt, out);
}

// Round 3
// 36.875 us; speedup vs baseline: 1.5124x; 1.0326x over previous
//
#include <hip/hip_runtime.h>
#include <math.h>

#define B_ 128
#define N_ 16800
#define N4_ 4200             // N_/4 (uint4/float4 units per row)
#define QUART4_ 1050         // uint4 units per A-block chunk (4 chunks/row)
#define NCHUNK 4
#define NBINS 2048
#define NBINS_P (NBINS + (NBINS >> 5))   // 2112 padded
#define FLT_EPS_ 1.1920929e-7f
#define MAXR 40

__device__ __forceinline__ float bce_of(float x, float y) {
    return fmaxf(x, 0.f) - x * y + __logf(1.f + __expf(-fabsf(x)));
}
// round-1 linear bin over [0,4): monotone, identical in kernels A and B
__device__ __forceinline__ unsigned int bin1_of(float v) {
    unsigned int b = (unsigned int)(v * 512.0f);
    return b > 2047u ? 2047u : b;
}
// refinement bin: monotone within [lo, lo+2048/scale)
__device__ __forceinline__ unsigned int binr_of(float v, float lo, float scale) {
    unsigned int b = (unsigned int)((v - lo) * scale);   // negative clamps to 0 on AMD cvt
    return b > 2047u ? 2047u : b;
}

// Padded-hist suffix select (wave 0). Finds digit d with S(d) >= remk > S(d+1)
// where S = suffix count; writes s_sel[0]=d, s_sel[1]=remk-S(d+1).
// Padded index p(i)=i+(i>>5) -> lane reads h[lane*33+j]: bank (lane+j)%32, conflict-free.
__device__ __forceinline__ void hist_select_p(const unsigned int* __restrict__ h,
                                              unsigned int remk, int lane, int wave,
                                              unsigned int* s_sel)
{
    if (wave == 0) {
        unsigned int c[32], lsum = 0u;
        #pragma unroll
        for (int j = 0; j < 32; ++j) { c[j] = h[lane * 33 + j]; lsum += c[j]; }
        unsigned int suf = lsum;
        #pragma unroll
        for (int off = 1; off < 64; off <<= 1) {
            unsigned int o = __shfl_down(suf, off);
            if (lane + off < 64) suf += o;
        }
        unsigned int r = suf;                 // suffix incl. this lane's bins
        #pragma unroll
        for (int j = 0; j < 32; ++j) {
            unsigned int scur = r; r -= c[j];
            if (scur >= remk && r < remk) {
                s_sel[0] = (unsigned int)(lane * 32 + j);
                s_sel[1] = remk - r;
            }
        }
    }
    __syncthreads();
}

// ---------------- Kernel A: streaming pass, full machine ----------------
__global__ __launch_bounds__(1024) void pass1_kernel(
    const float* __restrict__ pbboxs,
    const float* __restrict__ plabels,
    const float* __restrict__ gbboxs,
    const float* __restrict__ glabels,
    const float* __restrict__ ancs,
    unsigned int* __restrict__ g_hist,   // [B_][NBINS], pre-zeroed
    uint4*        __restrict__ g_lneg4,  // [B_][N4_]
    float*        __restrict__ g_lb2,    // [B_*NCHUNK] per-block partials
    float*        __restrict__ g_pbce2,
    int*          __restrict__ g_pn2)
{
    __shared__ unsigned int s_hist[NBINS];
    __shared__ float s_rf[16], s_rf2[16];
    __shared__ int   s_ri[16];

    const int tid  = threadIdx.x;
    const int lane = tid & 63;
    const int wave = tid >> 6;
    const int b    = blockIdx.x >> 2;
    const int h    = blockIdx.x & 3;

    s_hist[tid] = 0u; s_hist[tid + 1024] = 0u;
    __syncthreads();

    const uint4*  pl4 = (const uint4*)(plabels + (size_t)b * N_);
    const uint4*  gl4 = (const uint4*)(glabels + (size_t)b * N_);
    const float4* p4  = (const float4*)(pbboxs + (size_t)b * N_ * 4);
    const float4* g4  = (const float4*)(gbboxs + (size_t)b * N_ * 4);
    const float4* a4  = (const float4*)ancs;

    float acc_lb = 0.f, acc_pbce = 0.f;
    int   acc_pn = 0;

    for (int i = tid; i < QUART4_; i += 1024) {
        const int i4 = h * QUART4_ + i;
        uint4 xu = pl4[i4];
        uint4 yu = gl4[i4];
        unsigned int xb[4] = {xu.x, xu.y, xu.z, xu.w};
        unsigned int yb[4] = {yu.x, yu.y, yu.z, yu.w};
        unsigned int ob[4];
        #pragma unroll
        for (int j = 0; j < 4; ++j) {
            float x = __uint_as_float(xb[j]);
            float y = __uint_as_float(yb[j]);
            float bce = bce_of(x, y);
            bool  pos = (y > 0.f);
            float lneg = pos ? 0.f : bce;
            ob[j] = __float_as_uint(lneg);
            atomicAdd(&s_hist[bin1_of(lneg)], 1u);
            if (pos) {
                acc_pbce += bce;
                acc_pn   += 1;
                int n = 4 * i4 + j;
                float4 p = p4[n], g = g4[n], a = a4[n];
                float d0 = p.x - 10.f * __fdividef(g.x - a.x, a.z);
                float d1 = p.y - 10.f * __fdividef(g.y - a.y, a.w);
                float d2 = p.z - 5.f * __logf(__fdividef(g.z, a.z));
                float d3 = p.w - 5.f * __logf(__fdividef(g.w, a.w));
                float a0 = fabsf(d0), a1 = fabsf(d1), a2 = fabsf(d2), a3 = fabsf(d3);
                acc_lb += ((a0 < 1.f) ? 0.5f * d0 * d0 : a0 - 0.5f)
                        + ((a1 < 1.f) ? 0.5f * d1 * d1 : a1 - 0.5f)
                        + ((a2 < 1.f) ? 0.5f * d2 * d2 : a2 - 0.5f)
                        + ((a3 < 1.f) ? 0.5f * d3 * d3 : a3 - 0.5f);
            }
        }
        uint4 st; st.x = ob[0]; st.y = ob[1]; st.z = ob[2]; st.w = ob[3];
        g_lneg4[(size_t)b * N4_ + i4] = st;
    }

    #pragma unroll
    for (int off = 32; off > 0; off >>= 1) {
        acc_lb   += __shfl_xor(acc_lb, off);
        acc_pbce += __shfl_xor(acc_pbce, off);
        acc_pn   += __shfl_xor(acc_pn, off);
    }
    if (lane == 0) { s_rf[wave] = acc_lb; s_rf2[wave] = acc_pbce; s_ri[wave] = acc_pn; }
    __syncthreads();   // also completes s_hist
    if (tid == 0) {
        float t1 = 0.f, t2 = 0.f; int t3 = 0;
        for (int w = 0; w < 16; ++w) { t1 += s_rf[w]; t2 += s_rf2[w]; t3 += s_ri[w]; }
        g_lb2[blockIdx.x] = t1; g_pbce2[blockIdx.x] = t2; g_pn2[blockIdx.x] = t3;
    }
    // merge occupied bins to the per-row global histogram
    for (int i = tid; i < NBINS; i += 1024) {
        unsigned int c = s_hist[i];
        if (c) atomicAdd(&g_hist[b * NBINS + i], c);
    }
}

// ---------------- Kernel B: per-row exact select + final mean ----------------
__global__ __launch_bounds__(1024) void select_kernel(
    const uint4* __restrict__ g_lneg4,
    const unsigned int* __restrict__ g_hist,
    const float* __restrict__ g_lb2,
    const float* __restrict__ g_pbce2,
    const int*   __restrict__ g_pn2,
    float*        __restrict__ g_rowc,   // [3][B_]
    unsigned int* __restrict__ g_cnt,    // pre-zeroed
    float*        __restrict__ out)
{
    __shared__ unsigned int s_cand[N_];          // 67.2 KB (worst-case capacity)
    __shared__ unsigned int s_h[NBINS_P];        // 8.45 KB padded hist
    __shared__ unsigned int s_cnt2;
    __shared__ unsigned int s_sel[2];
    __shared__ float        s_sumgt;
    __shared__ unsigned int s_bmm[2];
    __shared__ unsigned int s_remk;
    __shared__ float s_plo[MAXR], s_pscale[MAXR];
    __shared__ unsigned int s_pb[MAXR];
    __shared__ float s_rf[16];
    __shared__ unsigned int s_umin[16], s_umax[16];
    __shared__ int s_last;

    const int tid  = threadIdx.x;
    const int lane = tid & 63;
    const int wave = tid >> 6;
    const int b    = blockIdx.x;

    const float row_lb   = g_lb2[4*b] + g_lb2[4*b+1] + g_lb2[4*b+2] + g_lb2[4*b+3];
    const float row_pbce = g_pbce2[4*b] + g_pbce2[4*b+1] + g_pbce2[4*b+2] + g_pbce2[4*b+3];
    const int   pn       = g_pn2[4*b] + g_pn2[4*b+1] + g_pn2[4*b+2] + g_pn2[4*b+3];
    int neg_num = 3 * pn; if (neg_num > N_) neg_num = N_;

    float sum_sel = 0.f;

    if (neg_num > 0) {
        for (int i = tid; i < NBINS; i += 1024) s_h[i + (i >> 5)] = g_hist[b * NBINS + i];
        if (tid == 0) { s_cnt2 = 0u; s_sumgt = 0.f; }
        __syncthreads();
        hist_select_p(s_h, (unsigned int)neg_num, lane, wave, s_sel);
        const unsigned int b1 = s_sel[0];
        unsigned int remk = s_sel[1];

        // single full-row scan: sum of greater bins, compact the threshold bin
        float sgt = 0.f;
        unsigned int bmin = 0xFFFFFFFFu, bmax = 0u;
        for (int i = tid; i < N4_; i += 1024) {
            uint4 v = g_lneg4[(size_t)b * N4_ + i];
            unsigned int va[4] = {v.x, v.y, v.z, v.w};
            #pragma unroll
            for (int j = 0; j < 4; ++j) {
                float f = __uint_as_float(va[j]);
                unsigned int bb = bin1_of(f);
                if (bb > b1) sgt += f;
                else if (bb == b1) {
                    unsigned int idx = atomicAdd(&s_cnt2, 1u);
                    s_cand[idx] = va[j];
                    bmin = (va[j] < bmin) ? va[j] : bmin;
                    bmax = (va[j] > bmax) ? va[j] : bmax;
                }
            }
        }
        #pragma unroll
        for (int off = 32; off > 0; off >>= 1) {
            sgt += __shfl_xor(sgt, off);
            unsigned int mn = __shfl_xor(bmin, off); bmin = (mn < bmin) ? mn : bmin;
            unsigned int mx = __shfl_xor(bmax, off); bmax = (mx > bmax) ? mx : bmax;
        }
        if (lane == 0) { s_rf[wave] = sgt; s_umin[wave] = bmin; s_umax[wave] = bmax; }
        __syncthreads();
        if (tid == 0) {
            float t = 0.f; unsigned int mn = 0xFFFFFFFFu, mx = 0u;
            for (int w = 0; w < 16; ++w) {
                t += s_rf[w];
                mn = (s_umin[w] < mn) ? s_umin[w] : mn;
                mx = (s_umax[w] > mx) ? s_umax[w] : mx;
            }
            s_sumgt += t; s_bmm[0] = mn; s_bmm[1] = mx;
        }
        __syncthreads();
        const int m = (int)s_cnt2;

        unsigned int tbits = s_bmm[0];
        for (int r = 0; r < MAXR; ++r) {
            if (s_bmm[0] == s_bmm[1]) { tbits = s_bmm[0]; break; }
            const float lo    = __uint_as_float(s_bmm[0]);
            const float scale = 2048.0f / (__uint_as_float(s_bmm[1]) - lo);
            if (tid == 0) { s_plo[r] = lo; s_pscale[r] = scale; }
            for (int i = tid; i < NBINS_P; i += 1024) s_h[i] = 0u;
            __syncthreads();
            for (int i = tid; i < m; i += 1024) {
                float f = __uint_as_float(s_cand[i]);
                bool ok = true;
                for (int j = 0; j < r; ++j)
                    if (binr_of(f, s_plo[j], s_pscale[j]) != s_pb[j]) { ok = false; break; }
                if (ok) {
                    unsigned int bb = binr_of(f, lo, scale);
                    atomicAdd(&s_h[bb + (bb >> 5)], 1u);
                }
            }
            __syncthreads();
            hist_select_p(s_h, remk, lane, wave, s_sel);
            const unsigned int d = s_sel[0], nk = s_sel[1];
            float sg2 = 0.f;
            unsigned int nmin = 0xFFFFFFFFu, nmax = 0u;
            for (int i = tid; i < m; i += 1024) {
                unsigned int vb = s_cand[i];
                float f = __uint_as_float(vb);
                bool ok = true;
                for (int j = 0; j < r; ++j)
                    if (binr_of(f, s_plo[j], s_pscale[j]) != s_pb[j]) { ok = false; break; }
                if (ok) {
                    unsigned int bb = binr_of(f, lo, scale);
                    if (bb > d) sg2 += f;
                    else if (bb == d) {
                        nmin = (vb < nmin) ? vb : nmin;
                        nmax = (vb > nmax) ? vb : nmax;
                    }
                }
            }
            #pragma unroll
            for (int off = 32; off > 0; off >>= 1) {
                sg2 += __shfl_xor(sg2, off);
                unsigned int mn = __shfl_xor(nmin, off); nmin = (mn < nmin) ? mn : nmin;
                unsigned int mx = __shfl_xor(nmax, off); nmax = (mx > nmax) ? mx : nmax;
            }
            if (lane == 0) { s_rf[wave] = sg2; s_umin[wave] = nmin; s_umax[wave] = nmax; }
            __syncthreads();
            if (tid == 0) {
                float t = 0.f; unsigned int mn = 0xFFFFFFFFu, mx = 0u;
                for (int w = 0; w < 16; ++w) {
                    t += s_rf[w];
                    mn = (s_umin[w] < mn) ? s_umin[w] : mn;
                    mx = (s_umax[w] > mx) ? s_umax[w] : mx;
                }
                s_sumgt += t; s_bmm[0] = mn; s_bmm[1] = mx;
                s_pb[r] = d; s_remk = nk;
            }
            __syncthreads();
            remk  = s_remk;
            tbits = s_bmm[0];
        }
        sum_sel = s_sumgt + (float)remk * __uint_as_float(tbits);
    }

    // per-row contribution (plain stores, deterministic) + last-block final mean
    if (tid == 0) {
        float nm = (pn > 0) ? 1.f : 0.f;
        float pc = fmaxf((float)pn, FLT_EPS_);
        g_rowc[b]          = row_lb * nm / pc;
        g_rowc[B_ + b]     = (row_pbce + sum_sel) * nm / pc;
        g_rowc[2 * B_ + b] = nm / pc;
        __threadfence();
        unsigned int old = atomicAdd(g_cnt, 1u);
        s_last = (old == (unsigned int)(B_ - 1)) ? 1 : 0;
    }
    __syncthreads();
    if (s_last && wave == 0) {
        // atomic reads bypass L1 (avoids stale lines); fixed tree -> deterministic
        float lb_t = atomicAdd(&g_rowc[lane], 0.f)          + atomicAdd(&g_rowc[lane + 64], 0.f);
        float ll_t = atomicAdd(&g_rowc[B_ + lane], 0.f)     + atomicAdd(&g_rowc[B_ + lane + 64], 0.f);
        float w_t  = atomicAdd(&g_rowc[2 * B_ + lane], 0.f) + atomicAdd(&g_rowc[2 * B_ + lane + 64], 0.f);
        #pragma unroll
        for (int off = 32; off > 0; off >>= 1) {
            lb_t += __shfl_xor(lb_t, off);
            ll_t += __shfl_xor(ll_t, off);
            w_t  += __shfl_xor(w_t, off);
        }
        if (lane == 0) {
            float LB = lb_t * (1.f / B_);
            float LL = ll_t * (1.f / B_);
            float W  = w_t  * (1.f / B_);
            out[0] = (LB + LL) * W;
            out[1] = LB;
            out[2] = LL;
        }
    }
}

extern "C" void kernel_launch(void* const* d_in, const int* in_sizes, int n_in,
                              void* d_out, int out_size, void* d_ws, size_t ws_size,
                              hipStream_t stream) {
    const float* pbboxs  = (const float*)d_in[0];
    const float* plabels = (const float*)d_in[1];
    const float* gbboxs  = (const float*)d_in[2];
    const float* glabels = (const float*)d_in[3];
    const float* ancs    = (const float*)d_in[4];
    float* out = (float*)d_out;

    char* ws = (char*)d_ws;
    // layout: [0,4) g_cnt | pad to 64 | g_hist 1 MB | g_lneg4 8.6 MB | partials | rowc
    unsigned int* g_cnt  = (unsigned int*)ws;
    unsigned int* g_hist = (unsigned int*)(ws + 64);
    uint4*        g_lneg4 = (uint4*)(ws + 64 + (size_t)B_ * NBINS * 4);          // 1048640
    size_t off = 64 + (size_t)B_ * NBINS * 4 + (size_t)B_ * N4_ * 16;            // 9650240
    float* g_lb2   = (float*)(ws + off);            off += (size_t)B_ * NCHUNK * 4;
    float* g_pbce2 = (float*)(ws + off);            off += (size_t)B_ * NCHUNK * 4;
    int*   g_pn2   = (int*)(ws + off);              off += (size_t)B_ * NCHUNK * 4;
    float* g_rowc  = (float*)(ws + off);

    // zero counter + per-row histograms (one contiguous region)
    hipMemsetAsync(d_ws, 0, 64 + (size_t)B_ * NBINS * 4, stream);

    pass1_kernel<<<B_ * NCHUNK, 1024, 0, stream>>>(
        pbboxs, plabels, gbboxs, glabels, ancs,
        g_hist, g_lneg4, g_lb2, g_pbce2, g_pn2);
    select_kernel<<<B_, 1024, 0, stream>>>(
        g_lneg4, g_hist, g_lb2, g_pbce2, g_pn2, g_rowc, g_cnt, out);
}

// Round 4
// 30.776 us; speedup vs baseline: 1.8122x; 1.1982x over previous
//
#include <hip/hip_runtime.h>
#include <math.h>

#define B_ 128
#define N_ 16800
#define N4_ 4200             // uint4 units per row
#define CHUNK4_ 1050         // uint4 units per chunk (4 chunks/row)
#define NCHUNK 4
#define NBLK_A (B_ * NCHUNK) // 512
#define NBINS 4096           // linear bins over [0, 8), width 1/512
#define BINSCALE 512.0f
#define FLT_EPS_ 1.1920929e-7f

__device__ __forceinline__ float bce_of(float x, float y) {
    return fmaxf(x, 0.f) - x * y + __logf(1.f + __expf(-fabsf(x)));
}
__device__ __forceinline__ unsigned int bin_of(float v) {
    unsigned int b = (unsigned int)(v * BINSCALE);
    return b > (NBINS - 1u) ? (NBINS - 1u) : b;
}

// ---------- Kernel A: streaming pass, 512 blocks (full machine) ----------
// Per chunk-block: bce for 4200 anchors, sparse SmoothL1 at positives,
// count+sum histograms in LDS, written out with plain coalesced stores
// (no zeroing, no global atomics needed anywhere).
__global__ __launch_bounds__(1024) void pass1_kernel(
    const float* __restrict__ pbboxs,
    const float* __restrict__ plabels,
    const float* __restrict__ gbboxs,
    const float* __restrict__ glabels,
    const float* __restrict__ ancs,
    unsigned int* __restrict__ g_hc,   // [NBLK_A][NBINS] counts
    float*        __restrict__ g_hs,   // [NBLK_A][NBINS] value sums
    float* __restrict__ g_lb,          // [NBLK_A] pos*sl1 partial
    float* __restrict__ g_pbce,        // [NBLK_A] pos*bce partial
    int*   __restrict__ g_pn)          // [NBLK_A] pos count partial
{
    __shared__ unsigned int s_hc[NBINS];   // 16 KB
    __shared__ float        s_hs[NBINS];   // 16 KB
    __shared__ float s_rf[16], s_rf2[16];
    __shared__ int   s_ri[16];

    const int tid  = threadIdx.x;
    const int lane = tid & 63;
    const int wave = tid >> 6;
    const int b    = blockIdx.x >> 2;
    const int h    = blockIdx.x & 3;

    #pragma unroll
    for (int j = 0; j < 4; ++j) { s_hc[tid + 1024 * j] = 0u; s_hs[tid + 1024 * j] = 0.f; }
    __syncthreads();

    const uint4*  pl4 = (const uint4*)(plabels + (size_t)b * N_) + h * CHUNK4_;
    const uint4*  gl4 = (const uint4*)(glabels + (size_t)b * N_) + h * CHUNK4_;
    const float4* p4  = (const float4*)(pbboxs + (size_t)b * N_ * 4);
    const float4* g4  = (const float4*)(gbboxs + (size_t)b * N_ * 4);
    const float4* a4  = (const float4*)ancs;

    float acc_lb = 0.f, acc_pbce = 0.f;
    int   acc_pn = 0;

    for (int i = tid; i < CHUNK4_; i += 1024) {
        uint4 xu = pl4[i];
        uint4 yu = gl4[i];
        unsigned int xb[4] = {xu.x, xu.y, xu.z, xu.w};
        unsigned int yb[4] = {yu.x, yu.y, yu.z, yu.w};
        #pragma unroll
        for (int j = 0; j < 4; ++j) {
            float x = __uint_as_float(xb[j]);
            float y = __uint_as_float(yb[j]);
            float bce = bce_of(x, y);
            bool  pos = (y > 0.f);
            float lneg = pos ? 0.f : bce;
            unsigned int bb = bin_of(lneg);
            atomicAdd(&s_hc[bb], 1u);
            atomicAdd(&s_hs[bb], lneg);
            if (pos) {
                acc_pbce += bce;
                acc_pn   += 1;
                int n = (h * CHUNK4_ + i) * 4 + j;
                float4 p = p4[n], g = g4[n], a = a4[n];
                float d0 = p.x - 10.f * __fdividef(g.x - a.x, a.z);
                float d1 = p.y - 10.f * __fdividef(g.y - a.y, a.w);
                float d2 = p.z - 5.f * __logf(__fdividef(g.z, a.z));
                float d3 = p.w - 5.f * __logf(__fdividef(g.w, a.w));
                float a0 = fabsf(d0), a1 = fabsf(d1), a2 = fabsf(d2), a3 = fabsf(d3);
                acc_lb += ((a0 < 1.f) ? 0.5f * d0 * d0 : a0 - 0.5f)
                        + ((a1 < 1.f) ? 0.5f * d1 * d1 : a1 - 0.5f)
                        + ((a2 < 1.f) ? 0.5f * d2 * d2 : a2 - 0.5f)
                        + ((a3 < 1.f) ? 0.5f * d3 * d3 : a3 - 0.5f);
            }
        }
    }

    #pragma unroll
    for (int off = 32; off > 0; off >>= 1) {
        acc_lb   += __shfl_xor(acc_lb, off);
        acc_pbce += __shfl_xor(acc_pbce, off);
        acc_pn   += __shfl_xor(acc_pn, off);
    }
    if (lane == 0) { s_rf[wave] = acc_lb; s_rf2[wave] = acc_pbce; s_ri[wave] = acc_pn; }
    __syncthreads();   // also completes s_hc/s_hs
    if (tid == 0) {
        float t1 = 0.f, t2 = 0.f; int t3 = 0;
        for (int w = 0; w < 16; ++w) { t1 += s_rf[w]; t2 += s_rf2[w]; t3 += s_ri[w]; }
        g_lb[blockIdx.x] = t1; g_pbce[blockIdx.x] = t2; g_pn[blockIdx.x] = t3;
    }

    // coalesced hist write-out: 1024 threads x one uint4/float4 each
    ((uint4*)(g_hc + (size_t)blockIdx.x * NBINS))[tid] = ((const uint4*)s_hc)[tid];
    ((float4*)(g_hs + (size_t)blockIdx.x * NBINS))[tid] = ((const float4*)s_hs)[tid];
}

// ---------- Kernel B: per-row threshold from histograms only ----------
// Thread t owns bins [4t, 4t+4). Inclusive suffix-scan (wave shuffle +
// cross-wave totals) locates b1 with Suffix(b1) >= k > Suffix(b1+1);
// sum of selected = sum of bins > b1 + remk * avg(bin b1).
__global__ __launch_bounds__(1024) void select_kernel(
    const unsigned int* __restrict__ g_hc,
    const float* __restrict__ g_hs,
    const int*   __restrict__ g_pn,
    float* __restrict__ g_sumsel)      // [B_]
{
    __shared__ unsigned int s_wtot[16];
    __shared__ float s_rf[16];
    __shared__ unsigned int s_sel[2];
    __shared__ float s_tavg;
    __shared__ int s_k;

    const int tid  = threadIdx.x;
    const int lane = tid & 63;
    const int wave = tid >> 6;
    const int b    = blockIdx.x;

    if (tid == 0) {
        int pn = g_pn[4*b] + g_pn[4*b+1] + g_pn[4*b+2] + g_pn[4*b+3];
        int k = 3 * pn; if (k > N_) k = N_;
        s_k = k;
    }
    __syncthreads();
    const unsigned int k = (unsigned int)s_k;
    if (k == 0u) {              // block-uniform
        if (tid == 0) g_sumsel[b] = 0.f;
        return;
    }

    unsigned int c[4] = {0u, 0u, 0u, 0u};
    float        s[4] = {0.f, 0.f, 0.f, 0.f};
    #pragma unroll
    for (int ch = 0; ch < NCHUNK; ++ch) {
        uint4  cu = ((const uint4*)(g_hc + (size_t)(b * NCHUNK + ch) * NBINS))[tid];
        float4 su = ((const float4*)(g_hs + (size_t)(b * NCHUNK + ch) * NBINS))[tid];
        c[0] += cu.x; c[1] += cu.y; c[2] += cu.z; c[3] += cu.w;
        s[0] += su.x; s[1] += su.y; s[2] += su.z; s[3] += su.w;
    }
    unsigned int pc = c[0] + c[1] + c[2] + c[3];

    // inclusive suffix within wave (higher lane = higher bins)
    unsigned int suf = pc;
    #pragma unroll
    for (int off = 1; off < 64; off <<= 1) {
        unsigned int o = __shfl_down(suf, off);
        if (lane + off < 64) suf += o;
    }
    if (lane == 0) s_wtot[wave] = suf;   // wave total
    __syncthreads();
    unsigned int above = 0u;
    for (int w = wave + 1; w < 16; ++w) above += s_wtot[w];
    unsigned int r = suf + above;        // suffix count from my first bin

    #pragma unroll
    for (int j = 0; j < 4; ++j) {
        unsigned int scur = r; r -= c[j];
        if (scur >= k && r < k) {        // exactly one (t,j) fires; c[j] >= 1 here
            s_sel[0] = (unsigned int)(tid * 4 + j);
            s_sel[1] = k - r;
            s_tavg   = s[j] / (float)c[j];
        }
    }
    __syncthreads();
    const unsigned int b1 = s_sel[0], remk = s_sel[1];

    float sg = 0.f;
    #pragma unroll
    for (int j = 0; j < 4; ++j)
        if ((unsigned int)(tid * 4 + j) > b1) sg += s[j];
    #pragma unroll
    for (int off = 32; off > 0; off >>= 1) sg += __shfl_xor(sg, off);
    if (lane == 0) s_rf[wave] = sg;
    __syncthreads();
    if (tid == 0) {
        float t = 0.f;
        for (int w = 0; w < 16; ++w) t += s_rf[w];
        g_sumsel[b] = t + (float)remk * s_tavg;
    }
}

// ---------- Kernel C: B=128 mean (1 block, deterministic) ----------
__global__ __launch_bounds__(128) void final_kernel(
    const float* __restrict__ g_lb,
    const float* __restrict__ g_pbce,
    const int*   __restrict__ g_pn,
    const float* __restrict__ g_sumsel,
    float* __restrict__ out)
{
    const int tid  = threadIdx.x;
    const int lane = tid & 63;
    const int wave = tid >> 6;

    int   pn = g_pn[4*tid] + g_pn[4*tid+1] + g_pn[4*tid+2] + g_pn[4*tid+3];
    float lb = g_lb[4*tid] + g_lb[4*tid+1] + g_lb[4*tid+2] + g_lb[4*tid+3];
    float pb = g_pbce[4*tid] + g_pbce[4*tid+1] + g_pbce[4*tid+2] + g_pbce[4*tid+3];

    float nm  = (pn > 0) ? 1.f : 0.f;
    float pcn = fmaxf((float)pn, FLT_EPS_);
    float lb_t = lb * nm / pcn;
    float ll_t = (pb + g_sumsel[tid]) * nm / pcn;
    float w_t  = nm / pcn;

    #pragma unroll
    for (int off = 32; off > 0; off >>= 1) {
        lb_t += __shfl_xor(lb_t, off);
        ll_t += __shfl_xor(ll_t, off);
        w_t  += __shfl_xor(w_t, off);
    }
    __shared__ float sh[3][2];
    if (lane == 0) { sh[0][wave] = lb_t; sh[1][wave] = ll_t; sh[2][wave] = w_t; }
    __syncthreads();
    if (tid == 0) {
        float LB = (sh[0][0] + sh[0][1]) * (1.f / B_);
        float LL = (sh[1][0] + sh[1][1]) * (1.f / B_);
        float W  = (sh[2][0] + sh[2][1]) * (1.f / B_);
        out[0] = (LB + LL) * W;
        out[1] = LB;
        out[2] = LL;
    }
}

extern "C" void kernel_launch(void* const* d_in, const int* in_sizes, int n_in,
                              void* d_out, int out_size, void* d_ws, size_t ws_size,
                              hipStream_t stream) {
    const float* pbboxs  = (const float*)d_in[0];
    const float* plabels = (const float*)d_in[1];
    const float* gbboxs  = (const float*)d_in[2];
    const float* glabels = (const float*)d_in[3];
    const float* ancs    = (const float*)d_in[4];
    float* out = (float*)d_out;

    char* ws = (char*)d_ws;
    unsigned int* g_hc = (unsigned int*)ws;                         // 8 MB
    float* g_hs        = (float*)(ws + (size_t)NBLK_A * NBINS * 4); // 8 MB
    size_t off = (size_t)NBLK_A * NBINS * 8;
    float* g_lb     = (float*)(ws + off);  off += NBLK_A * 4;
    float* g_pbce   = (float*)(ws + off);  off += NBLK_A * 4;
    int*   g_pn     = (int*)(ws + off);    off += NBLK_A * 4;
    float* g_sumsel = (float*)(ws + off);

    // every workspace word is written before it is read -> no memset needed
    pass1_kernel<<<NBLK_A, 1024, 0, stream>>>(
        pbboxs, plabels, gbboxs, glabels, ancs, g_hc, g_hs, g_lb, g_pbce, g_pn);
    select_kernel<<<B_, 1024, 0, stream>>>(g_hc, g_hs, g_pn, g_sumsel);
    final_kernel<<<1, 128, 0, stream>>>(g_lb, g_pbce, g_pn, g_sumsel, out);
}